// Round 12
// baseline (284.205 us; speedup 1.0000x reference)
//
#include <hip/hip_runtime.h>
#include <hip/hip_bf16.h>
#include <stdint.h>

typedef __attribute__((ext_vector_type(4))) float f32x4;
typedef __attribute__((ext_vector_type(8))) short short8;

__device__ __forceinline__ ushort f2b(float f) {
    union { __hip_bfloat16 h; ushort u; } c;
    c.h = __float2bfloat16(f);
    return c.u;
}

// async global->LDS, 16B per lane. LDS dest is wave-uniform; HW adds lane*16.
__device__ __forceinline__ void gload_lds16(const void* g, void* lds) {
    __builtin_amdgcn_global_load_lds((const __attribute__((address_space(1))) void*)g,
                                     (__attribute__((address_space(3))) void*)lds,
                                     16, 0, 0);
}

#define BARRIER()  asm volatile("s_barrier" ::: "memory")
#define VMCNT6()   asm volatile("s_waitcnt vmcnt(6)" ::: "memory")
#define VMCNT8()   asm volatile("s_waitcnt vmcnt(8)" ::: "memory")

// ---- fused pre-pass: x -> bf16 (y==0), w * blockscale -> bf16 (y==1) --------
__global__ void conv_both_kernel(const float* __restrict__ x, ushort* __restrict__ xb, long n8x,
                                 const float* __restrict__ w, const float* __restrict__ sinv,
                                 ushort* __restrict__ wb, int K, int nbk, long n8w) {
    long i = (long)blockIdx.x * blockDim.x + threadIdx.x;
    if (blockIdx.y == 0) {
        if (i >= n8x) return;
        const float4* xv = (const float4*)x;
        float4 v0 = xv[i * 2], v1 = xv[i * 2 + 1];
        short8 r;
        r[0] = (short)f2b(v0.x); r[1] = (short)f2b(v0.y); r[2] = (short)f2b(v0.z); r[3] = (short)f2b(v0.w);
        r[4] = (short)f2b(v1.x); r[5] = (short)f2b(v1.y); r[6] = (short)f2b(v1.z); r[7] = (short)f2b(v1.w);
        *(short8*)&xb[i * 8] = r;
    } else {
        if (i >= n8w) return;
        long e = i * 8;
        int o, c;
        if (K == 4096) { o = (int)(e >> 12); c = (int)(e & 4095); }
        else { o = (int)(e / K); c = (int)(e - (long)o * K); }
        const float s = sinv[(o >> 7) * nbk + (c >> 7)];
        const float4* wv = (const float4*)(w + e);
        float4 v0 = wv[0], v1 = wv[1];
        short8 r;
        r[0] = (short)f2b(v0.x * s); r[1] = (short)f2b(v0.y * s); r[2] = (short)f2b(v0.z * s); r[3] = (short)f2b(v0.w * s);
        r[4] = (short)f2b(v1.x * s); r[5] = (short)f2b(v1.y * s); r[6] = (short)f2b(v1.z * s); r[7] = (short)f2b(v1.w * s);
        *(short8*)&wb[e] = r;
    }
}

// ---- main GEMM: 256x256 tile, BK=64, 8 waves (2Mx4N) ------------------------
// m201-style counted-vmcnt pipeline: staging in K-HALF grain (16KB halves,
// 2 gloads/thread/phase, uniform stream), vmcnt(6) at EVERY phase end ->
// 3 halves always in flight, each load gets ~3 phases of flight, never
// drains to 0. LDS: [buf][op][kh][256 rows][32 shorts], chunk ^= (row>>1)&3.
// Stage map (period 8): q1:(t+1).A.K1  q2:(t+1).B.K1  q3:(t+2).A.K0  q4:(t+2).B.K0
__global__ __launch_bounds__(512, 2)
void gemm256_kernel(const ushort* __restrict__ A, const ushort* __restrict__ Bm,
                    const float* __restrict__ bias, float* __restrict__ C,
                    int M, int N, int K) {
    __shared__ alignas(16) short sm[2][32768];  // [buf][ A: kh*8192+row*32 | B: +16384 ]

    const int tid  = threadIdx.x;
    const int lane = tid & 63;
    const int wid  = tid >> 6;
    const int wr   = wid >> 2;          // 0..1  -> 128-row slice of C
    const int wc   = wid & 3;           // 0..3  -> 64-col slice of C
    const int nbn  = N >> 8;

    // XCD-aware bijective swizzle (launcher guarantees gridDim.x % 8 == 0)
    const int nwg = gridDim.x;
    const int swz = (blockIdx.x & 7) * (nwg >> 3) + (blockIdx.x >> 3);
    const int bm  = swz / nbn;
    const int bn  = swz % nbn;

    const short* gA = (const short*)A + (size_t)bm * 256 * K;
    const short* gB = (const short*)Bm + (size_t)bn * 256 * K;

    // stage one K-half (256 rows x 32 cols, 16KB): thread -> 2 gloads.
    // row R = wid*32 + g*16 + (lane>>2); src chunk pre-swizzled by (R>>1)&3
    // so linear LDS write == swizzled layout.
    auto STAGE = [&](const short* gOp, int opOff, int kh, int kt, int buf) {
#pragma unroll
        for (int g = 0; g < 2; ++g) {
            int R = wid * 32 + g * 16 + (lane >> 2);
            int chunk = (lane & 3) ^ ((R >> 1) & 3);
            const short* src = gOp + (size_t)R * K + kt * 64 + kh * 32 + chunk * 8;
            gload_lds16(src, &sm[buf][opOff + kh * 8192 + wid * 1024 + g * 512]);
        }
    };

    // fragment reads: addr = kh*8192 + row*32 + ((lane>>4)^((row>>1)&3))*8
    auto LD_A = [&](int buf, int kh, int mh, short8 (&a)[4]) {
#pragma unroll
        for (int m = 0; m < 4; ++m) {
            int row = wr * 128 + mh * 64 + m * 16 + (lane & 15);
            a[m] = *(const short8*)&sm[buf][kh * 8192 + row * 32 + ((((lane >> 4) ^ ((row >> 1) & 3))) << 3)];
        }
    };
    auto LD_B = [&](int buf, int kh, short8 (&b)[4]) {
#pragma unroll
        for (int n = 0; n < 4; ++n) {
            int row = wc * 64 + n * 16 + (lane & 15);
            b[n] = *(const short8*)&sm[buf][16384 + kh * 8192 + row * 32 + ((((lane >> 4) ^ ((row >> 1) & 3))) << 3)];
        }
    };

    f32x4 acc[8][4] = {};

    auto MFMA_H = [&](int off, short8 (&af)[4], short8 (&bf)[4], int m0, int m1) {
#pragma unroll
        for (int m = m0; m < m1; ++m)
#pragma unroll
            for (int n = 0; n < 4; ++n)
                acc[off + m][n] = __builtin_amdgcn_mfma_f32_16x16x32_bf16(af[m], bf[n], acc[off + m][n], 0, 0, 0);
    };

    const int nkt = K >> 6;   // >= 32 and even (launcher enforces K % 2048 == 0)

    short8 aCur[4], bCur[4];  // carried: current tile's (mh0,kk0) A-frags + kk0 B-frags

    auto KSTEP = [&](int t) {
        const int b  = t & 1;
        const int nb = b ^ 1;
        const int t1 = (t + 1 < nkt) ? t + 1 : nkt - 1;
        const int t2 = (t + 2 < nkt) ? t + 2 : nkt - 1;

        short8 aB[4], aC[4], aD[4], bB[4];

        // q1: (mh0,kk0); embed aB(kh0,mh1); stage (t+1).A.K1 -> nb
        BARRIER();
        __builtin_amdgcn_s_setprio(1);
        MFMA_H(0, aCur, bCur, 0, 2);
        LD_A(b, 0, 1, aB);
        MFMA_H(0, aCur, bCur, 2, 4);
        __builtin_amdgcn_s_setprio(0);
        STAGE(gA, 0, 1, t1, nb);
        VMCNT6();

        // q2: (mh1,kk0); embed aC(kh1,mh0), bB(kh1); stage (t+1).B.K1 -> nb
        BARRIER();
        __builtin_amdgcn_s_setprio(1);
        MFMA_H(4, aB, bCur, 0, 2);
        LD_A(b, 1, 0, aC);
        LD_B(b, 1, bB);
        MFMA_H(4, aB, bCur, 2, 4);
        __builtin_amdgcn_s_setprio(0);
        STAGE(gB, 16384, 1, t1, nb);
        VMCNT6();

        // q3: (mh0,kk1); embed aD(kh1,mh1); stage (t+2).A.K0 -> b
        BARRIER();
        __builtin_amdgcn_s_setprio(1);
        MFMA_H(0, aC, bB, 0, 2);
        LD_A(b, 1, 1, aD);
        MFMA_H(0, aC, bB, 2, 4);
        __builtin_amdgcn_s_setprio(0);
        STAGE(gA, 0, 0, t2, b);
        VMCNT6();

        // q4: (mh1,kk1); embed pre-read of tile t+1's (kk0) frags from nb;
        //     stage (t+2).B.K0 -> b
        BARRIER();
        __builtin_amdgcn_s_setprio(1);
        MFMA_H(4, aD, bB, 0, 2);
        LD_A(nb, 0, 0, aCur);
        LD_B(nb, 0, bCur);
        MFMA_H(4, aD, bB, 2, 4);
        __builtin_amdgcn_s_setprio(0);
        STAGE(gB, 16384, 0, t2, b);
        VMCNT6();
    };

    // ---- prologue: t0 all 4 halves + t1.K0 halves (12 loads); vmcnt(8)
    //      retires exactly t0.K0 (A,B) for the pre-read. ----
    {
        STAGE(gA, 0, 0, 0, 0);       // t0.A.K0
        STAGE(gB, 16384, 0, 0, 0);   // t0.B.K0
        STAGE(gA, 0, 1, 0, 0);       // t0.A.K1
        STAGE(gB, 16384, 1, 0, 0);   // t0.B.K1
        STAGE(gA, 0, 0, 1, 1);       // t1.A.K0
        STAGE(gB, 16384, 0, 1, 1);   // t1.B.K0
        VMCNT8();
        BARRIER();
        LD_A(0, 0, 0, aCur);
        LD_B(0, 0, bCur);
    }

    // 2 K-tiles per body: 8 phases visible to the scheduler
    for (int t = 0; t < nkt; t += 2) {
        KSTEP(t);
        KSTEP(t + 1);
    }

    // ---- epilogue: C = acc + bias (fp32); regs only, no barrier needed ----
    const int r0 = bm * 256 + wr * 128 + (lane >> 4) * 4;
    const int c0 = bn * 256 + wc * 64 + (lane & 15);
#pragma unroll
    for (int n = 0; n < 4; ++n) {
        float bv = bias[c0 + n * 16];
#pragma unroll
        for (int m = 0; m < 8; ++m) {
#pragma unroll
            for (int r = 0; r < 4; ++r) {
                C[(size_t)(r0 + m * 16 + r) * N + (c0 + n * 16)] = acc[m][n][r] + bv;
            }
        }
    }
}

// ---- fallback (shape-generic, slow but correct) -----------------------------
__global__ void fallback_gemm(const float* __restrict__ x, const float* __restrict__ w,
                              const float* __restrict__ sinv, const float* __restrict__ bias,
                              float* __restrict__ out, int M, int N, int K) {
    int n = blockIdx.x * 64 + (threadIdx.x & 63);
    int m = blockIdx.y * 4 + (threadIdx.x >> 6);
    if (m >= M || n >= N) return;
    const int nbk = K >> 7;
    float acc = 0.f;
    for (int k = 0; k < K; ++k)
        acc += x[(size_t)m * K + k] * w[(size_t)n * K + k] * sinv[(n >> 7) * nbk + (k >> 7)];
    out[(size_t)m * N + n] = acc + bias[n];
}

extern "C" void kernel_launch(void* const* d_in, const int* in_sizes, int n_in,
                              void* d_out, int out_size, void* d_ws, size_t ws_size,
                              hipStream_t stream) {
    const float* x    = (const float*)d_in[0];
    const float* w    = (const float*)d_in[1];
    const float* sinv = (const float*)d_in[2];
    const float* bias = (const float*)d_in[3];
    float* out        = (float*)d_out;

    const int O = in_sizes[3];                  // 4096
    const int K = in_sizes[1] / O;              // 4096
    const int M = (int)((long)in_sizes[0] / K); // B*S = 4096
    const int N = O;

    const size_t need = ((size_t)M * K + (size_t)N * K) * sizeof(ushort);
    const int nwg = (M / 256) * (N / 256);
    const bool ok = ws_size >= need && (M % 256 == 0) && (N % 256 == 0) &&
                    (K % 128 == 0) && (nwg % 8 == 0) && ((long)M * K % 2048 == 0) &&
                    (K % 2048 == 0);
    if (ok) {
        ushort* xb = (ushort*)d_ws;
        ushort* wb = xb + (size_t)M * K;
        long n8x = (long)M * K / 8;
        long n8w = (long)N * K / 8;
        long n8m = (n8x > n8w) ? n8x : n8w;
        dim3 cg((unsigned)((n8m + 255) / 256), 2);
        conv_both_kernel<<<cg, 256, 0, stream>>>(x, xb, n8x, w, sinv, wb, K, K >> 7, n8w);
        gemm256_kernel<<<dim3(nwg), 512, 0, stream>>>(xb, wb, bias, out, M, N, K);
    } else {
        dim3 g(N / 64, (M + 3) / 4);
        fallback_gemm<<<g, 256, 0, stream>>>(x, w, sinv, bias, out, M, N, K);
    }
}